// Round 8
// baseline (486.229 us; speedup 1.0000x reference)
//
#include <hip/hip_runtime.h>

#define NN 50000
#define NE 1600000
#define DD 64
#define NPB 196          // nodes per bucket
#define HPB 98           // nodes per build half-bucket task
#define NBKT 256         // buckets
#define NCHUNK 640       // edge chunks (2500 edges each)
#define CG 625           // int4-groups per chunk
#define SLOT 24          // LDS records per bucket per chunk
#define SSTR 25          // LDS stride pad
#define S1CAP 1024       // per-(bucket,shard) region
#define SPCAP 512        // per-bucket spill region
#define ELLW 80          // ELL row width (pad-to-16)
#define GRID 512         // mega-kernel grid: 2 blocks/CU exactly
#define NTILE 1563       // ceil(50016/32) 32-node fused tiles

typedef __attribute__((ext_vector_type(8))) short bf16x8;
typedef __attribute__((ext_vector_type(4))) float f32x4;
typedef __attribute__((ext_vector_type(2))) float f32x2;

static __device__ __forceinline__ unsigned short f2bf(float f) {
    unsigned int u = __float_as_uint(f);
    unsigned int r = (u + 0x7FFFu + ((u >> 16) & 1u)) >> 16;   // RNE
    return (unsigned short)r;
}
static __device__ __forceinline__ unsigned int pk_fp8x4(float a, float b, float c, float d) {
    unsigned int p = __builtin_amdgcn_cvt_pk_fp8_f32(a, b, 0u, false);
    p = __builtin_amdgcn_cvt_pk_fp8_f32(c, d, p, true);
    return p;
}

// ---------------------------------------------------------------------------
// Epoch-counting grid barrier. Requires all GRID blocks co-resident
// (guaranteed: 2 blocks/CU x 256 CU; LDS 53KB<=80KB, launch_bounds caps
// VGPR<=64). bar[0]=arrival cnt, bar[1]=epoch; both zeroed by memset each
// run. Device-scope atomics + acquire/release give cross-XCD visibility
// (G16). Bounded spin: deadlock degrades to a visible FAIL, not a hang.
// ---------------------------------------------------------------------------
static __device__ __forceinline__ void gridbar(int* bar) {
    __syncthreads();
    if (threadIdx.x == 0) {
        int my = __hip_atomic_load(&bar[1], __ATOMIC_RELAXED, __HIP_MEMORY_SCOPE_AGENT);
        __threadfence();
        if (atomicAdd(&bar[0], 1) == GRID - 1) {
            bar[0] = 0;
            __threadfence();
            __hip_atomic_store(&bar[1], my + 1, __ATOMIC_RELEASE, __HIP_MEMORY_SCOPE_AGENT);
        } else {
            int t = 0;
            while (__hip_atomic_load(&bar[1], __ATOMIC_ACQUIRE, __HIP_MEMORY_SCOPE_AGENT) == my) {
                __builtin_amdgcn_s_sleep(4);
                if (++t > (1 << 22)) break;   // failsafe: FAIL visibly, never hang
            }
        }
        __threadfence();
    }
    __syncthreads();
}

// R21 hot loop body: 16 records (4 per lane-group) of one node into packed accs
#define PROC16(r, s01, s23)                                                   \
    {                                                                         \
        unsigned int v0 = f8[(r.x & 0xFFFF) * 16 + l16];                      \
        unsigned int v1 = f8[(r.y & 0xFFFF) * 16 + l16];                      \
        unsigned int v2 = f8[(r.z & 0xFFFF) * 16 + l16];                      \
        unsigned int v3 = f8[(r.w & 0xFFFF) * 16 + l16];                      \
        float w0 = __uint_as_float(r.x & 0xFFFF0000u);                        \
        float w1 = __uint_as_float(r.y & 0xFFFF0000u);                        \
        float w2 = __uint_as_float(r.z & 0xFFFF0000u);                        \
        float w3 = __uint_as_float(r.w & 0xFFFF0000u);                        \
        f32x2 lo, hi, wp;                                                     \
        lo = __builtin_amdgcn_cvt_pk_f32_fp8(v0, false);                      \
        hi = __builtin_amdgcn_cvt_pk_f32_fp8(v0, true);                       \
        wp = (f32x2){w0, w0}; s01 += wp * lo; s23 += wp * hi;                 \
        lo = __builtin_amdgcn_cvt_pk_f32_fp8(v1, false);                      \
        hi = __builtin_amdgcn_cvt_pk_f32_fp8(v1, true);                       \
        wp = (f32x2){w1, w1}; s01 += wp * lo; s23 += wp * hi;                 \
        lo = __builtin_amdgcn_cvt_pk_f32_fp8(v2, false);                      \
        hi = __builtin_amdgcn_cvt_pk_f32_fp8(v2, true);                       \
        wp = (f32x2){w2, w2}; s01 += wp * lo; s23 += wp * hi;                 \
        lo = __builtin_amdgcn_cvt_pk_f32_fp8(v3, false);                      \
        hi = __builtin_amdgcn_cvt_pk_f32_fp8(v3, true);                       \
        wp = (f32x2){w3, w3}; s01 += wp * lo; s23 += wp * hi;                 \
    }

// ---------------------------------------------------------------------------
// Fused layer as a device function: grid-stride over 32-node tiles; each
// block = two independent 8-wave sub-blocks (sub = wave>>3), each running
// the R21-proven flow (2 nodes/wave interleaved chains + row prefetch) on
// its own 16-node half-tile. Node>=NN handled as deg-0/no-store.
// ---------------------------------------------------------------------------
static __device__ void fused_phase(
    const ushort* __restrict__ Xb, const unsigned int* __restrict__ f8,
    const int* __restrict__ cnt, const unsigned int* __restrict__ csr,
    const ushort* __restrict__ Wb, const float* __restrict__ bias,
    float* __restrict__ out, ushort* __restrict__ outb,
    unsigned char* __restrict__ outf8,
    ushort (*xL)[72], ushort (*aggL)[72])
{
    int tid = threadIdx.x;
    int wave = tid >> 6, lane = tid & 63;
    int sub = wave >> 3, w8 = wave & 7;
    int g = lane >> 4, l16 = lane & 15;

    for (int t = blockIdx.x; t < NTILE; t += GRID) {
        int base16 = t * 32 + sub * 16;
        int nodeA = base16 + w8;            // half-tile rows 0..7
        int nodeB = base16 + w8 + 8;        // half-tile rows 8..15
        bool vA = nodeA < NN, vB = nodeB < NN;
        int rowA = sub * 16 + w8, rowB = rowA + 8;

        if (lane < 16) {
            ushort4 z = make_ushort4(0, 0, 0, 0);
            *(ushort4*)&xL[rowA][l16 * 4] = vA
                ? *(const ushort4*)&Xb[(size_t)nodeA * DD + l16 * 4] : z;
            *(ushort4*)&xL[rowB][l16 * 4] = vB
                ? *(const ushort4*)&Xb[(size_t)nodeB * DD + l16 * 4] : z;
        }

        int ndA = vA ? cnt[nodeA] : 0;
        int ndB = vB ? cnt[nodeB] : 0;
        int nA = ndA < ELLW ? ndA : ELLW;
        int nB = ndB < ELLW ? ndB : ELLW;
        int nA16 = (nA + 15) & ~15;
        int nB16 = (nB + 15) & ~15;
        int imax = nA16 > nB16 ? nA16 : nB16;
        const unsigned int* rpA = csr + (size_t)(vA ? nodeA : 0) * ELLW + g * 4;
        const unsigned int* rpB = csr + (size_t)(vB ? nodeB : 0) * ELLW + g * 4;
        f32x2 sA01 = {0.f, 0.f}, sA23 = {0.f, 0.f};
        f32x2 sB01 = {0.f, 0.f}, sB23 = {0.f, 0.f};

        uint4 rA, rB;
        if (0 < nA16) rA = *(const uint4*)(rpA);
        if (0 < nB16) rB = *(const uint4*)(rpB);

        for (int i = 0; i < imax; i += 16) {
            uint4 rAn, rBn;
            bool doAn = (i + 16) < nA16, doBn = (i + 16) < nB16;
            if (doAn) rAn = *(const uint4*)(rpA + i + 16);
            if (doBn) rBn = *(const uint4*)(rpB + i + 16);
            if (i < nA16) PROC16(rA, sA01, sA23);
            if (i < nB16) PROC16(rB, sB01, sB23);
            rA = rAn; rB = rBn;
        }

        float aA0 = sA01.x, aA1 = sA01.y, aA2 = sA23.x, aA3 = sA23.y;
        float aB0 = sB01.x, aB1 = sB01.y, aB2 = sB23.x, aB3 = sB23.y;
        aA0 += __shfl_xor(aA0, 16); aA0 += __shfl_xor(aA0, 32);
        aA1 += __shfl_xor(aA1, 16); aA1 += __shfl_xor(aA1, 32);
        aA2 += __shfl_xor(aA2, 16); aA2 += __shfl_xor(aA2, 32);
        aA3 += __shfl_xor(aA3, 16); aA3 += __shfl_xor(aA3, 32);
        aB0 += __shfl_xor(aB0, 16); aB0 += __shfl_xor(aB0, 32);
        aB1 += __shfl_xor(aB1, 16); aB1 += __shfl_xor(aB1, 32);
        aB2 += __shfl_xor(aB2, 16); aB2 += __shfl_xor(aB2, 32);
        aB3 += __shfl_xor(aB3, 16); aB3 += __shfl_xor(aB3, 32);

        if (lane < 16) {
            float dmA = (float)(ndA > 1 ? ndA : 1);
            float dmB = (float)(ndB > 1 ? ndB : 1);
            ushort4 oA, oB;
            oA.x = f2bf(aA0 / dmA); oA.y = f2bf(aA1 / dmA);
            oA.z = f2bf(aA2 / dmA); oA.w = f2bf(aA3 / dmA);
            oB.x = f2bf(aB0 / dmB); oB.y = f2bf(aB1 / dmB);
            oB.z = f2bf(aB2 / dmB); oB.w = f2bf(aB3 / dmB);
            *(ushort4*)&aggL[rowA][l16 * 4] = oA;
            *(ushort4*)&aggL[rowB][l16 * 4] = oB;
        }
        __syncthreads();

        if (w8 < 4) {
            f32x4 acc = (f32x4){0.f, 0.f, 0.f, 0.f};
#pragma unroll
            for (int ki = 0; ki < 4; ++ki) {
                const ushort* ap = (ki < 2) ? &xL[sub * 16 + l16][ki * 32 + g * 8]
                                            : &aggL[sub * 16 + l16][(ki - 2) * 32 + g * 8];
                bf16x8 af = *(const bf16x8*)ap;
                bf16x8 bfrag = *(const bf16x8*)&Wb[(size_t)(w8 * 16 + l16) * 128 + ki * 32 + g * 8];
                acc = __builtin_amdgcn_mfma_f32_16x16x32_bf16(af, bfrag, acc, 0, 0, 0);
            }
            int col = w8 * 16 + l16;
            float bv = bias[col];
#pragma unroll
            for (int r = 0; r < 4; ++r) {
                int grow = base16 + g * 4 + r;   // C/D: col=lane&15, row=quad*4+reg
                if (grow < NN) {
                    float v = fmaxf(acc[r] + bv, 0.f);
                    if (out)  out[(size_t)grow * DD + col] = v;
                    if (outb) outb[(size_t)grow * DD + col] = f2bf(v);
                    if (outf8) {
                        unsigned int p = __builtin_amdgcn_cvt_pk_fp8_f32(v, v, 0u, false);
                        outf8[(size_t)grow * DD + col] = (unsigned char)(p & 0xFFu);
                    }
                }
            }
        }
        __syncthreads();   // before next tile reuses xL/aggL
    }
}

// ---------------------------------------------------------------------------
// R23 MEGA-KERNEL: BIN+CAST -> bar -> BUILD -> bar -> LAYER1 -> bar ->
// LAYER2 in one dispatch. Phases are the R18/R21-proven bodies re-shaped
// to grid-stride at 512x1024 (2 blocks/CU guaranteed). Deletes 3 dispatch
// boundaries + their launch overhead; memset folded down to one.
// ---------------------------------------------------------------------------
__global__ __launch_bounds__(1024, 8) void mega(
    const int* __restrict__ ei, const float* __restrict__ ew,
    int* __restrict__ gcur, int* __restrict__ gspillc, int* bar,
    int2* __restrict__ buf1, int2* __restrict__ spill,
    unsigned int* __restrict__ csr, int* __restrict__ cnt,
    const float* __restrict__ x, ushort* __restrict__ xb,
    unsigned int* __restrict__ xf8,
    const float* __restrict__ W1, const float* __restrict__ W2,
    ushort* __restrict__ W1b, ushort* __restrict__ W2b,
    const float* __restrict__ b1, const float* __restrict__ b2,
    ushort* __restrict__ h1b, unsigned char* __restrict__ h1f8,
    float* __restrict__ out)
{
    __shared__ union {
        struct { int2 slot[NBKT * SSTR]; int lcnt[NBKT]; int lbase[NBKT]; } bin; // 53,248 B
        struct { int cur[HPB]; int cnts[9]; } bld;
        struct { ushort xL[32][72]; ushort aggL[32][72]; } fl;                   //  9,216 B
    } sm;

    int tid = threadIdx.x;
    int wave = tid >> 6, lane = tid & 63;

    // ================= phase 1a: edge binning (640 chunks, grid-stride) ====
    {
        const int4*   s4 = (const int4*)ei;
        const int4*   d4 = ((const int4*)ei) + NE / 4;
        const float4* w4 = (const float4*)ew;
        for (int c = blockIdx.x; c < NCHUNK; c += GRID) {
            if (tid < NBKT) sm.bin.lcnt[tid] = 0;
            __syncthreads();
            int shard = c & 7;
            int g0 = c * CG;
            if (tid < CG) {
                int4 sv = s4[g0 + tid];
                int4 dv = d4[g0 + tid];
                float4 wv = w4[g0 + tid];
#pragma unroll
                for (int k = 0; k < 4; ++k) {
                    int s = (k == 0) ? sv.x : (k == 1) ? sv.y : (k == 2) ? sv.z : sv.w;
                    int d = (k == 0) ? dv.x : (k == 1) ? dv.y : (k == 2) ? dv.z : dv.w;
                    float w = (k == 0) ? wv.x : (k == 1) ? wv.y : (k == 2) ? wv.z : wv.w;
                    int bkt = s / NPB;
                    int sloc = s - bkt * NPB;
                    int2 rec = make_int2(d | ((int)f2bf(w) << 16), sloc);
                    int pos = atomicAdd(&sm.bin.lcnt[bkt], 1);
                    if (pos < SLOT) {
                        sm.bin.slot[bkt * SSTR + pos] = rec;
                    } else {
                        int sp = atomicAdd(&gspillc[bkt], 1);
                        if (sp < SPCAP) spill[bkt * SPCAP + sp] = rec;
                    }
                }
            }
            __syncthreads();
            if (tid < NBKT) {               // one reservation per (chunk,bucket)
                int b = tid;
                int n = sm.bin.lcnt[b]; if (n > SLOT) n = SLOT;
                sm.bin.lcnt[b] = n;
                sm.bin.lbase[b] = (n > 0) ? atomicAdd(&gcur[b * 8 + shard], n) : 0;
            }
            __syncthreads();
            // flush: 16 waves x 16 buckets (4 iters of 4 x 16-lane groups)
            int grp = lane >> 4, l16 = lane & 15;
#pragma unroll 4
            for (int jj = 0; jj < 4; ++jj) {
                int b = wave * 16 + jj * 4 + grp;
                int n = sm.bin.lcnt[b];
                int base = sm.bin.lbase[b];
                int2* dst = &buf1[((size_t)b * 8 + shard) * S1CAP];
                if (l16 < n) {
                    int2 rec = sm.bin.slot[b * SSTR + l16];
                    int p = base + l16;
                    if (p < S1CAP) dst[p] = rec;
                    else { int sp = atomicAdd(&gspillc[b], 1);
                           if (sp < SPCAP) spill[b * SPCAP + sp] = rec; }
                }
                if (l16 + 16 < n) {         // n <= 24: only lanes 0..7
                    int2 rec = sm.bin.slot[b * SSTR + l16 + 16];
                    int p = base + l16 + 16;
                    if (p < S1CAP) dst[p] = rec;
                    else { int sp = atomicAdd(&gspillc[b], 1);
                           if (sp < SPCAP) spill[b * SPCAP + sp] = rec; }
                }
            }
            __syncthreads();                // before lcnt reuse (blocks < 128)
        }
    }

    // ================= phase 1b: x / W casts (grid-stride) =================
    for (int i = blockIdx.x * 1024 + tid; i < 804096; i += GRID * 1024) {
        if (i < 800000) {                   // NN*DD/4 float4 groups
            float4 v = ((const float4*)x)[i];
            ushort4 o;
            o.x = f2bf(v.x); o.y = f2bf(v.y); o.z = f2bf(v.z); o.w = f2bf(v.w);
            ((ushort4*)xb)[i] = o;
            xf8[i] = pk_fp8x4(v.x, v.y, v.z, v.w);
        } else {                            // 4096 W float4 groups
            int j = i - 800000;
            const float* src = (j < 2048) ? W1 : W2;
            ushort* dst = (j < 2048) ? W1b : W2b;
            int jj = j & 2047;
            float4 v = ((const float4*)src)[jj];
            ushort4 o;
            o.x = f2bf(v.x); o.y = f2bf(v.y); o.z = f2bf(v.z); o.w = f2bf(v.w);
            ((ushort4*)dst)[jj] = o;
        }
    }

    gridbar(bar);

    // ================= phase 2: ELL build (512 tasks = 512 blocks) =========
    {
        int bkt = blockIdx.x >> 1;
        int nlo = (blockIdx.x & 1) * HPB;

        if (tid < HPB) sm.bld.cur[tid] = 0;
        if (tid >= 128 && tid < 137) {      // parallel count prefetch
            int sh = tid - 128;
            int n = (sh < 8) ? gcur[bkt * 8 + sh] : gspillc[bkt];
            int cap = (sh < 8) ? S1CAP : SPCAP;
            sm.bld.cnts[sh] = n < cap ? n : cap;
        }
        __syncthreads();

        {                                   // 8 shards concurrently, 128 thr each
            int sh = tid >> 7, lt = tid & 127;
            int n = sm.bld.cnts[sh];
            const int2* rp = buf1 + ((size_t)bkt * 8 + sh) * S1CAP;
            for (int i = lt; i < n; i += 128) {
                int2 r = rp[i];
                int node = r.y - nlo;
                if ((unsigned)node < HPB) {
                    int pos = atomicAdd(&sm.bld.cur[node], 1);
                    if (pos < ELLW)
                        csr[((size_t)(bkt * NPB + r.y)) * ELLW + pos] = (unsigned int)r.x;
                }
            }
        }
        {                                   // spill region: all threads
            int n = sm.bld.cnts[8];
            const int2* rp = spill + (size_t)bkt * SPCAP;
            for (int i = tid; i < n; i += 1024) {
                int2 r = rp[i];
                int node = r.y - nlo;
                if ((unsigned)node < HPB) {
                    int pos = atomicAdd(&sm.bld.cur[node], 1);
                    if (pos < ELLW)
                        csr[((size_t)(bkt * NPB + r.y)) * ELLW + pos] = (unsigned int)r.x;
                }
            }
        }
        __syncthreads();

        if (tid < HPB) {
            int node = bkt * NPB + nlo + tid;
            if (node < NN) {
                int deg = sm.bld.cur[tid];
                cnt[node] = deg;
                int c = deg < ELLW ? deg : ELLW;
                int c16 = (c + 15) & ~15;   // <= 80 always
                for (int p = c; p < c16; ++p)
                    csr[(size_t)node * ELLW + p] = 0u;
            }
        }
    }

    gridbar(bar);

    // ================= phase 3: layer 1 ====================================
    fused_phase(xb, xf8, cnt, csr, W1b, b1,
                nullptr, h1b, h1f8, sm.fl.xL, sm.fl.aggL);

    gridbar(bar);

    // ================= phase 4: layer 2 ====================================
    fused_phase(h1b, (const unsigned int*)h1f8, cnt, csr, W2b, b2,
                out, nullptr, nullptr, sm.fl.xL, sm.fl.aggL);
}

// ---------------------------------------------------------------------------
extern "C" void kernel_launch(void* const* d_in, const int* in_sizes, int n_in,
                              void* d_out, int out_size, void* d_ws, size_t ws_size,
                              hipStream_t stream)
{
    const float* x  = (const float*)d_in[0];
    const int*   ei = (const int*)d_in[1];
    const float* ew = (const float*)d_in[2];
    const float* W1 = (const float*)d_in[3];
    const float* b1 = (const float*)d_in[4];
    const float* W2 = (const float*)d_in[5];
    const float* b2 = (const float*)d_in[6];
    float* out = (float*)d_out;

    // workspace layout, ~53.3 MB (16B-aligned offsets)
    char* ws = (char*)d_ws;
    int*          gcur    = (int*)ws;                          //      8,192 B
    int*          gspillc = (int*)(ws + 8192);                 //      1,024 B
    int*          bar     = (int*)(ws + 9216);                 //         16 B
    int2*         buf1    = (int2*)(ws + 16384);               // 16,777,216 B
    int2*         spill   = (int2*)(ws + 16793600);            //  1,048,576 B
    unsigned int* csr     = (unsigned int*)(ws + 17842176);    // 16,056,320 B (ELL 80/node)
    int*          cnt     = (int*)(ws + 33898496);             //    200,704 B
    ushort*       xb      = (ushort*)(ws + 34099200);          //  6,400,000 B
    ushort*       h1b     = (ushort*)(ws + 40499200);          //  6,400,000 B
    ushort*       W1b     = (ushort*)(ws + 46899200);          //     16,384 B
    ushort*       W2b     = (ushort*)(ws + 46915584);          //     16,384 B
    unsigned int* xf8     = (unsigned int*)(ws + 46931968);    //  3,200,000 B
    unsigned char* h1f8   = (unsigned char*)(ws + 50131968);   //  3,200,000 B

    hipMemsetAsync(gcur, 0, 9232, stream);   // gcur + gspillc + bar

    mega<<<GRID, 1024, 0, stream>>>(ei, ew, gcur, gspillc, bar, buf1, spill,
                                    csr, cnt, x, xb, xf8, W1, W2, W1b, W2b,
                                    b1, b2, h1b, h1f8, out);
}

// Round 9
// 459.838 us; speedup vs baseline: 1.0574x; 1.0574x over previous
//
#include <hip/hip_runtime.h>

#define NN 50000
#define NE 1600000
#define DD 64
#define NPB 196          // nodes per bucket
#define HPB 98           // nodes per build half-bucket task
#define NBKT 256         // buckets
#define NCHUNK 640       // edge chunks (2500 edges each)
#define CG 625           // int4-groups per chunk
#define SLOT 24          // LDS records per bucket per chunk
#define SSTR 25          // LDS stride pad
#define S1CAP 1024       // per-(bucket,shard) region
#define SPCAP 512        // per-bucket spill region
#define ELLW 80          // ELL row width (pad-to-16)
#define GRID 512         // mega grid: 2 blocks/CU co-resident
#define NT16 3125        // 16-node fused tiles (NN/16 exactly)

typedef __attribute__((ext_vector_type(8))) short bf16x8;
typedef __attribute__((ext_vector_type(4))) float f32x4;
typedef __attribute__((ext_vector_type(2))) float f32x2;

static __device__ __forceinline__ unsigned short f2bf(float f) {
    unsigned int u = __float_as_uint(f);
    unsigned int r = (u + 0x7FFFu + ((u >> 16) & 1u)) >> 16;   // RNE
    return (unsigned short)r;
}
static __device__ __forceinline__ unsigned int pk_fp8x4(float a, float b, float c, float d) {
    unsigned int p = __builtin_amdgcn_cvt_pk_fp8_f32(a, b, 0u, false);
    p = __builtin_amdgcn_cvt_pk_fp8_f32(c, d, p, true);
    return p;
}

// ---------------------------------------------------------------------------
// Epoch-counting grid barrier (all GRID blocks co-resident: LDS 53KB -> 3
// blocks/CU, VGPR<=128 -> >=2 blocks/CU, 512 = 2x256). Device-scope atomics
// + acquire/release (G16). Bounded spin: fails visibly, never hangs.
// ---------------------------------------------------------------------------
static __device__ __forceinline__ void gridbar(int* bar) {
    __syncthreads();
    if (threadIdx.x == 0) {
        int my = __hip_atomic_load(&bar[1], __ATOMIC_RELAXED, __HIP_MEMORY_SCOPE_AGENT);
        __threadfence();
        if (atomicAdd(&bar[0], 1) == GRID - 1) {
            bar[0] = 0;
            __threadfence();
            __hip_atomic_store(&bar[1], my + 1, __ATOMIC_RELEASE, __HIP_MEMORY_SCOPE_AGENT);
        } else {
            int t = 0;
            while (__hip_atomic_load(&bar[1], __ATOMIC_ACQUIRE, __HIP_MEMORY_SCOPE_AGENT) == my) {
                __builtin_amdgcn_s_sleep(4);
                if (++t > (1 << 22)) break;   // failsafe
            }
        }
        __threadfence();
    }
    __syncthreads();
}

// R21 hot loop body: 16 records (4 per lane-group) of one node into packed accs
#define PROC16(r, s01, s23)                                                   \
    {                                                                         \
        unsigned int v0 = f8[(r.x & 0xFFFF) * 16 + l16];                      \
        unsigned int v1 = f8[(r.y & 0xFFFF) * 16 + l16];                      \
        unsigned int v2 = f8[(r.z & 0xFFFF) * 16 + l16];                      \
        unsigned int v3 = f8[(r.w & 0xFFFF) * 16 + l16];                      \
        float w0 = __uint_as_float(r.x & 0xFFFF0000u);                        \
        float w1 = __uint_as_float(r.y & 0xFFFF0000u);                        \
        float w2 = __uint_as_float(r.z & 0xFFFF0000u);                        \
        float w3 = __uint_as_float(r.w & 0xFFFF0000u);                        \
        f32x2 lo, hi, wp;                                                     \
        lo = __builtin_amdgcn_cvt_pk_f32_fp8(v0, false);                      \
        hi = __builtin_amdgcn_cvt_pk_f32_fp8(v0, true);                       \
        wp = (f32x2){w0, w0}; s01 += wp * lo; s23 += wp * hi;                 \
        lo = __builtin_amdgcn_cvt_pk_f32_fp8(v1, false);                      \
        hi = __builtin_amdgcn_cvt_pk_f32_fp8(v1, true);                       \
        wp = (f32x2){w1, w1}; s01 += wp * lo; s23 += wp * hi;                 \
        lo = __builtin_amdgcn_cvt_pk_f32_fp8(v2, false);                      \
        hi = __builtin_amdgcn_cvt_pk_f32_fp8(v2, true);                       \
        wp = (f32x2){w2, w2}; s01 += wp * lo; s23 += wp * hi;                 \
        lo = __builtin_amdgcn_cvt_pk_f32_fp8(v3, false);                      \
        hi = __builtin_amdgcn_cvt_pk_f32_fp8(v3, true);                       \
        wp = (f32x2){w3, w3}; s01 += wp * lo; s23 += wp * hi;                 \
    }

// ---------------------------------------------------------------------------
// R21-proven fused layer as a device function: grid-stride over 16-node
// tiles; 8 waves, 2 nodes/wave interleaved chains + row prefetch.
// ---------------------------------------------------------------------------
static __device__ void fused_phase(
    const ushort* __restrict__ Xb, const unsigned int* __restrict__ f8,
    const int* __restrict__ cnt, const unsigned int* __restrict__ csr,
    const ushort* __restrict__ Wb, const float* __restrict__ bias,
    float* __restrict__ out, ushort* __restrict__ outb,
    unsigned char* __restrict__ outf8,
    ushort (*xL)[72], ushort (*aggL)[72])
{
    int tid = threadIdx.x;
    int wave = tid >> 6, lane = tid & 63;   // wave 0..7
    int g = lane >> 4, l16 = lane & 15;

    for (int t = blockIdx.x; t < NT16; t += GRID) {
        int base = t * 16;
        int nodeA = base + wave;            // rows 0..7
        int nodeB = base + wave + 8;        // rows 8..15

        if (lane < 16) {
            *(ushort4*)&xL[wave][l16 * 4] =
                *(const ushort4*)&Xb[(size_t)nodeA * DD + l16 * 4];
            *(ushort4*)&xL[wave + 8][l16 * 4] =
                *(const ushort4*)&Xb[(size_t)nodeB * DD + l16 * 4];
        }

        int ndA = cnt[nodeA], ndB = cnt[nodeB];
        int nA = ndA < ELLW ? ndA : ELLW;
        int nB = ndB < ELLW ? ndB : ELLW;
        int nA16 = (nA + 15) & ~15;
        int nB16 = (nB + 15) & ~15;
        int imax = nA16 > nB16 ? nA16 : nB16;
        const unsigned int* rpA = csr + (size_t)nodeA * ELLW + g * 4;
        const unsigned int* rpB = csr + (size_t)nodeB * ELLW + g * 4;
        f32x2 sA01 = {0.f, 0.f}, sA23 = {0.f, 0.f};
        f32x2 sB01 = {0.f, 0.f}, sB23 = {0.f, 0.f};

        uint4 rA, rB;
        if (0 < nA16) rA = *(const uint4*)(rpA);
        if (0 < nB16) rB = *(const uint4*)(rpB);

        for (int i = 0; i < imax; i += 16) {
            uint4 rAn, rBn;
            bool doAn = (i + 16) < nA16, doBn = (i + 16) < nB16;
            if (doAn) rAn = *(const uint4*)(rpA + i + 16);
            if (doBn) rBn = *(const uint4*)(rpB + i + 16);
            if (i < nA16) PROC16(rA, sA01, sA23);
            if (i < nB16) PROC16(rB, sB01, sB23);
            rA = rAn; rB = rBn;
        }

        float aA0 = sA01.x, aA1 = sA01.y, aA2 = sA23.x, aA3 = sA23.y;
        float aB0 = sB01.x, aB1 = sB01.y, aB2 = sB23.x, aB3 = sB23.y;
        aA0 += __shfl_xor(aA0, 16); aA0 += __shfl_xor(aA0, 32);
        aA1 += __shfl_xor(aA1, 16); aA1 += __shfl_xor(aA1, 32);
        aA2 += __shfl_xor(aA2, 16); aA2 += __shfl_xor(aA2, 32);
        aA3 += __shfl_xor(aA3, 16); aA3 += __shfl_xor(aA3, 32);
        aB0 += __shfl_xor(aB0, 16); aB0 += __shfl_xor(aB0, 32);
        aB1 += __shfl_xor(aB1, 16); aB1 += __shfl_xor(aB1, 32);
        aB2 += __shfl_xor(aB2, 16); aB2 += __shfl_xor(aB2, 32);
        aB3 += __shfl_xor(aB3, 16); aB3 += __shfl_xor(aB3, 32);

        if (lane < 16) {
            float dmA = (float)(ndA > 1 ? ndA : 1);
            float dmB = (float)(ndB > 1 ? ndB : 1);
            ushort4 oA, oB;
            oA.x = f2bf(aA0 / dmA); oA.y = f2bf(aA1 / dmA);
            oA.z = f2bf(aA2 / dmA); oA.w = f2bf(aA3 / dmA);
            oB.x = f2bf(aB0 / dmB); oB.y = f2bf(aB1 / dmB);
            oB.z = f2bf(aB2 / dmB); oB.w = f2bf(aB3 / dmB);
            *(ushort4*)&aggL[wave][l16 * 4] = oA;
            *(ushort4*)&aggL[wave + 8][l16 * 4] = oB;
        }
        __syncthreads();

        if (wave < 4) {
            f32x4 acc = (f32x4){0.f, 0.f, 0.f, 0.f};
#pragma unroll
            for (int ki = 0; ki < 4; ++ki) {
                const ushort* ap = (ki < 2) ? &xL[l16][ki * 32 + g * 8]
                                            : &aggL[l16][(ki - 2) * 32 + g * 8];
                bf16x8 af = *(const bf16x8*)ap;
                bf16x8 bfrag = *(const bf16x8*)&Wb[(size_t)(wave * 16 + l16) * 128 + ki * 32 + g * 8];
                acc = __builtin_amdgcn_mfma_f32_16x16x32_bf16(af, bfrag, acc, 0, 0, 0);
            }
            int col = wave * 16 + l16;
            float bv = bias[col];
#pragma unroll
            for (int r = 0; r < 4; ++r) {
                int grow = base + g * 4 + r;   // C/D: col=lane&15, row=quad*4+reg
                float v = fmaxf(acc[r] + bv, 0.f);
                if (out)  out[(size_t)grow * DD + col] = v;
                if (outb) outb[(size_t)grow * DD + col] = f2bf(v);
                if (outf8) {
                    unsigned int p = __builtin_amdgcn_cvt_pk_fp8_f32(v, v, 0u, false);
                    outf8[(size_t)grow * DD + col] = (unsigned char)(p & 0xFFu);
                }
            }
        }
        __syncthreads();   // before next tile reuses xL/aggL
    }
}

// ---------------------------------------------------------------------------
// R24 MEGA-KERNEL, spill-fixed: 512 thr, launch_bounds(512,4) -> VGPR cap
// 128 (R23's (1024,8) capped at 32 and spilled ~150MB scratch: FETCH+WRITE
// 105+104MB, VALUBusy 9%). Phases: BIN+CAST -> bar -> BUILD -> bar ->
// LAYER1 -> bar -> LAYER2. All phase bodies are the R18/R21-proven shapes.
// ---------------------------------------------------------------------------
__global__ __launch_bounds__(512, 4) void mega(
    const int* __restrict__ ei, const float* __restrict__ ew,
    int* __restrict__ gcur, int* __restrict__ gspillc, int* bar,
    int2* __restrict__ buf1, int2* __restrict__ spill,
    unsigned int* __restrict__ csr, int* __restrict__ cnt,
    const float* __restrict__ x, ushort* __restrict__ xb,
    unsigned int* __restrict__ xf8,
    const float* __restrict__ W1, const float* __restrict__ W2,
    ushort* __restrict__ W1b, ushort* __restrict__ W2b,
    const float* __restrict__ b1, const float* __restrict__ b2,
    ushort* __restrict__ h1b, unsigned char* __restrict__ h1f8,
    float* __restrict__ out)
{
    __shared__ union {
        struct { int2 slot[NBKT * SSTR]; int lcnt[NBKT]; int lbase[NBKT]; } bin; // 53,248 B
        struct { int cur[HPB]; int cnts[9]; } bld;
        struct { ushort xL[16][72]; ushort aggL[16][72]; } fl;                   //  4,608 B
    } sm;

    int tid = threadIdx.x;
    int wave = tid >> 6, lane = tid & 63;

    // ================= phase 1a: edge binning (640 chunks, grid-stride) ====
    {
        const int4*   s4 = (const int4*)ei;
        const int4*   d4 = ((const int4*)ei) + NE / 4;
        const float4* w4 = (const float4*)ew;
        for (int c = blockIdx.x; c < NCHUNK; c += GRID) {
            if (tid < NBKT) sm.bin.lcnt[tid] = 0;
            __syncthreads();
            int shard = c & 7;
            int g0 = c * CG;
            for (int it = 0; it < 2; ++it) {
                int idx = it * 512 + tid;
                if (idx >= CG) break;
                int4 sv = s4[g0 + idx];
                int4 dv = d4[g0 + idx];
                float4 wv = w4[g0 + idx];
#pragma unroll
                for (int k = 0; k < 4; ++k) {
                    int s = (k == 0) ? sv.x : (k == 1) ? sv.y : (k == 2) ? sv.z : sv.w;
                    int d = (k == 0) ? dv.x : (k == 1) ? dv.y : (k == 2) ? dv.z : dv.w;
                    float w = (k == 0) ? wv.x : (k == 1) ? wv.y : (k == 2) ? wv.z : wv.w;
                    int bkt = s / NPB;
                    int sloc = s - bkt * NPB;
                    int2 rec = make_int2(d | ((int)f2bf(w) << 16), sloc);
                    int pos = atomicAdd(&sm.bin.lcnt[bkt], 1);
                    if (pos < SLOT) {
                        sm.bin.slot[bkt * SSTR + pos] = rec;
                    } else {
                        int sp = atomicAdd(&gspillc[bkt], 1);
                        if (sp < SPCAP) spill[bkt * SPCAP + sp] = rec;
                    }
                }
            }
            __syncthreads();
            if (tid < NBKT) {               // one reservation per (chunk,bucket)
                int b = tid;
                int n = sm.bin.lcnt[b]; if (n > SLOT) n = SLOT;
                sm.bin.lcnt[b] = n;
                sm.bin.lbase[b] = (n > 0) ? atomicAdd(&gcur[b * 8 + shard], n) : 0;
            }
            __syncthreads();
            // flush: 8 waves x 32 buckets (8 iters of 4 x 16-lane groups)
            int grp = lane >> 4, l16 = lane & 15;
#pragma unroll 4
            for (int jj = 0; jj < 8; ++jj) {
                int b = wave * 32 + jj * 4 + grp;
                int n = sm.bin.lcnt[b];
                int base = sm.bin.lbase[b];
                int2* dst = &buf1[((size_t)b * 8 + shard) * S1CAP];
                if (l16 < n) {
                    int2 rec = sm.bin.slot[b * SSTR + l16];
                    int p = base + l16;
                    if (p < S1CAP) dst[p] = rec;
                    else { int sp = atomicAdd(&gspillc[b], 1);
                           if (sp < SPCAP) spill[b * SPCAP + sp] = rec; }
                }
                if (l16 + 16 < n) {         // n <= 24: only lanes 0..7
                    int2 rec = sm.bin.slot[b * SSTR + l16 + 16];
                    int p = base + l16 + 16;
                    if (p < S1CAP) dst[p] = rec;
                    else { int sp = atomicAdd(&gspillc[b], 1);
                           if (sp < SPCAP) spill[b * SPCAP + sp] = rec; }
                }
            }
            __syncthreads();                // before lcnt reuse
        }
    }

    // ================= phase 1b: x / W casts (grid-stride) =================
    for (int i = blockIdx.x * 512 + tid; i < 804096; i += GRID * 512) {
        if (i < 800000) {                   // NN*DD/4 float4 groups
            float4 v = ((const float4*)x)[i];
            ushort4 o;
            o.x = f2bf(v.x); o.y = f2bf(v.y); o.z = f2bf(v.z); o.w = f2bf(v.w);
            ((ushort4*)xb)[i] = o;
            xf8[i] = pk_fp8x4(v.x, v.y, v.z, v.w);
        } else {                            // 4096 W float4 groups
            int j = i - 800000;
            const float* src = (j < 2048) ? W1 : W2;
            ushort* dst = (j < 2048) ? W1b : W2b;
            int jj = j & 2047;
            float4 v = ((const float4*)src)[jj];
            ushort4 o;
            o.x = f2bf(v.x); o.y = f2bf(v.y); o.z = f2bf(v.z); o.w = f2bf(v.w);
            ((ushort4*)dst)[jj] = o;
        }
    }

    gridbar(bar);

    // ================= phase 2: ELL build (512 tasks = 512 blocks) =========
    {
        int bkt = blockIdx.x >> 1;
        int nlo = (blockIdx.x & 1) * HPB;

        if (tid < HPB) sm.bld.cur[tid] = 0;
        if (tid >= 128 && tid < 137) {      // parallel count prefetch
            int sh = tid - 128;
            int n = (sh < 8) ? gcur[bkt * 8 + sh] : gspillc[bkt];
            int cap = (sh < 8) ? S1CAP : SPCAP;
            sm.bld.cnts[sh] = n < cap ? n : cap;
        }
        __syncthreads();

        {                                   // 8 shards concurrently, 64 thr each
            int sh = tid >> 6, lt = tid & 63;
            int n = sm.bld.cnts[sh];
            const int2* rp = buf1 + ((size_t)bkt * 8 + sh) * S1CAP;
            for (int i = lt; i < n; i += 64) {
                int2 r = rp[i];
                int node = r.y - nlo;
                if ((unsigned)node < HPB) {
                    int pos = atomicAdd(&sm.bld.cur[node], 1);
                    if (pos < ELLW)
                        csr[((size_t)(bkt * NPB + r.y)) * ELLW + pos] = (unsigned int)r.x;
                }
            }
        }
        {                                   // spill region: all threads
            int n = sm.bld.cnts[8];
            const int2* rp = spill + (size_t)bkt * SPCAP;
            for (int i = tid; i < n; i += 512) {
                int2 r = rp[i];
                int node = r.y - nlo;
                if ((unsigned)node < HPB) {
                    int pos = atomicAdd(&sm.bld.cur[node], 1);
                    if (pos < ELLW)
                        csr[((size_t)(bkt * NPB + r.y)) * ELLW + pos] = (unsigned int)r.x;
                }
            }
        }
        __syncthreads();

        if (tid < HPB) {
            int node = bkt * NPB + nlo + tid;
            if (node < NN) {
                int deg = sm.bld.cur[tid];
                cnt[node] = deg;
                int c = deg < ELLW ? deg : ELLW;
                int c16 = (c + 15) & ~15;   // <= 80 always
                for (int p = c; p < c16; ++p)
                    csr[(size_t)node * ELLW + p] = 0u;
            }
        }
    }

    gridbar(bar);

    // ================= phase 3: layer 1 ====================================
    fused_phase(xb, xf8, cnt, csr, W1b, b1,
                nullptr, h1b, h1f8, sm.fl.xL, sm.fl.aggL);

    gridbar(bar);

    // ================= phase 4: layer 2 ====================================
    fused_phase(h1b, (const unsigned int*)h1f8, cnt, csr, W2b, b2,
                out, nullptr, nullptr, sm.fl.xL, sm.fl.aggL);
}

// ---------------------------------------------------------------------------
extern "C" void kernel_launch(void* const* d_in, const int* in_sizes, int n_in,
                              void* d_out, int out_size, void* d_ws, size_t ws_size,
                              hipStream_t stream)
{
    const float* x  = (const float*)d_in[0];
    const int*   ei = (const int*)d_in[1];
    const float* ew = (const float*)d_in[2];
    const float* W1 = (const float*)d_in[3];
    const float* b1 = (const float*)d_in[4];
    const float* W2 = (const float*)d_in[5];
    const float* b2 = (const float*)d_in[6];
    float* out = (float*)d_out;

    // workspace layout, ~53.3 MB (16B-aligned offsets)
    char* ws = (char*)d_ws;
    int*          gcur    = (int*)ws;                          //      8,192 B
    int*          gspillc = (int*)(ws + 8192);                 //      1,024 B
    int*          bar     = (int*)(ws + 9216);                 //         16 B
    int2*         buf1    = (int2*)(ws + 16384);               // 16,777,216 B
    int2*         spill   = (int2*)(ws + 16793600);            //  1,048,576 B
    unsigned int* csr     = (unsigned int*)(ws + 17842176);    // 16,056,320 B (ELL 80/node)
    int*          cnt     = (int*)(ws + 33898496);             //    200,704 B
    ushort*       xb      = (ushort*)(ws + 34099200);          //  6,400,000 B
    ushort*       h1b     = (ushort*)(ws + 40499200);          //  6,400,000 B
    ushort*       W1b     = (ushort*)(ws + 46899200);          //     16,384 B
    ushort*       W2b     = (ushort*)(ws + 46915584);          //     16,384 B
    unsigned int* xf8     = (unsigned int*)(ws + 46931968);    //  3,200,000 B
    unsigned char* h1f8   = (unsigned char*)(ws + 50131968);   //  3,200,000 B

    hipMemsetAsync(gcur, 0, 9232, stream);   // gcur + gspillc + bar

    mega<<<GRID, 512, 0, stream>>>(ei, ew, gcur, gspillc, bar, buf1, spill,
                                   csr, cnt, x, xb, xf8, W1, W2, W1b, W2b,
                                   b1, b2, h1b, h1f8, out);
}

// Round 10
// 172.614 us; speedup vs baseline: 2.8169x; 2.6640x over previous
//
#include <hip/hip_runtime.h>

#define NN 50000
#define NE 1600000
#define DD 64
#define NPB 196          // nodes per bucket
#define HPB 98           // nodes per build_ell half-bucket block
#define NBKT 256         // buckets (NPB*NBKT = 50176 >= NN)
#define CHUNK 2500       // edges per bin block (640 blocks * 2500 = NE)
#define NBLK 640
#define SLOT 24          // LDS records per bucket: lambda=9.77, +4.5 sigma
#define SSTR 25          // LDS stride pad (R12-proven)
#define S1CAP 1024       // per-(bucket,shard) region: lambda=781, +8.7 sigma
#define SPCAP 512        // per-bucket global spill region
#define ELLW 80          // fixed records per node row (pad-to-16); P(deg>80)~1e-12

typedef __attribute__((ext_vector_type(8))) short bf16x8;   // 8 bf16 = 4 VGPR
typedef __attribute__((ext_vector_type(4))) float f32x4;
typedef __attribute__((ext_vector_type(2))) float f32x2;

static __device__ __forceinline__ unsigned short f2bf(float f) {
    unsigned int u = __float_as_uint(f);
    unsigned int r = (u + 0x7FFFu + ((u >> 16) & 1u)) >> 16;   // RNE
    return (unsigned short)r;
}
// pack 4 fp32 -> 4 x fp8-e4m3 (OCP, HW cvt)
static __device__ __forceinline__ unsigned int pk_fp8x4(float a, float b, float c, float d) {
    unsigned int p = __builtin_amdgcn_cvt_pk_fp8_f32(a, b, 0u, false);
    p = __builtin_amdgcn_cvt_pk_fp8_f32(c, d, p, true);
    return p;
}

// ---------------------------------------------------------------------------
// R15/R18 FUSED prep + binning (proven; part of the 172.4us best config).
// Blocks 0..639: LDS-staged edge binning. Blocks 640..3764: x cast.
// Blocks 3765..3780: W cast. gcur/gspillc zeroed by hipMemsetAsync before.
// Record: .x = dst(16) | w_bf16<<16, .y = node-within-bucket.
// ---------------------------------------------------------------------------
__global__ __launch_bounds__(256) void prep_bin(
    const int* __restrict__ ei, const float* __restrict__ ew,
    int* __restrict__ gcur, int* __restrict__ gspillc,
    int2* __restrict__ buf1, int2* __restrict__ spill,
    const float* __restrict__ x, ushort* __restrict__ xb,
    unsigned int* __restrict__ xf8,
    const float* __restrict__ W1, const float* __restrict__ W2,
    ushort* __restrict__ W1b, ushort* __restrict__ W2b)
{
    __shared__ int2 slot[NBKT * SSTR];   // 50 KB
    __shared__ int  lcnt[NBKT];
    __shared__ int  lbase[NBKT];
    int tid = threadIdx.x;
    int blk = blockIdx.x;

    if (blk >= NBLK) {
        int pb = blk - NBLK;
        if (pb < 3125) {                   // 3125*256 = 800000 = NN*DD/4
            int i = pb * 256 + tid;
            float4 v = ((const float4*)x)[i];
            ushort4 o;
            o.x = f2bf(v.x); o.y = f2bf(v.y); o.z = f2bf(v.z); o.w = f2bf(v.w);
            ((ushort4*)xb)[i] = o;
            xf8[i] = pk_fp8x4(v.x, v.y, v.z, v.w);
        } else {                           // 16*256 = 4096 float4 groups
            int i = (pb - 3125) * 256 + tid;
            const float* src = (i < 2048) ? W1 : W2;
            ushort* dst = (i < 2048) ? W1b : W2b;
            int j = i & 2047;
            float4 v = ((const float4*)src)[j];
            ushort4 o;
            o.x = f2bf(v.x); o.y = f2bf(v.y); o.z = f2bf(v.z); o.w = f2bf(v.w);
            ((ushort4*)dst)[j] = o;
        }
        return;
    }

    int shard = blk & 7;
    for (int b = tid; b < NBKT; b += 256) lcnt[b] = 0;
    __syncthreads();

    // 4-wide edge loads: CHUNK/4 = 625 int4-groups per block
    int g0 = blk * (CHUNK / 4);            // int4-group base
    const int4*   s4 = (const int4*)ei;            // src words
    const int4*   d4 = ((const int4*)ei) + NE / 4; // dst words
    const float4* w4 = (const float4*)ew;
    for (int it = 0; it < 3; ++it) {
        int idx = it * 256 + tid;
        if (idx >= CHUNK / 4) break;
        int4 sv = s4[g0 + idx];
        int4 dv = d4[g0 + idx];
        float4 wv = w4[g0 + idx];
#pragma unroll
        for (int k = 0; k < 4; ++k) {
            int s = (k == 0) ? sv.x : (k == 1) ? sv.y : (k == 2) ? sv.z : sv.w;
            int d = (k == 0) ? dv.x : (k == 1) ? dv.y : (k == 2) ? dv.z : dv.w;
            float w = (k == 0) ? wv.x : (k == 1) ? wv.y : (k == 2) ? wv.z : wv.w;
            int bkt = s / NPB;
            int sloc = s - bkt * NPB;
            int2 rec = make_int2(d | ((int)f2bf(w) << 16), sloc);
            int pos = atomicAdd(&lcnt[bkt], 1);
            if (pos < SLOT) {
                slot[bkt * SSTR + pos] = rec;
            } else {
                int sp = atomicAdd(&gspillc[bkt], 1);
                if (sp < SPCAP) spill[bkt * SPCAP + sp] = rec;
            }
        }
    }
    __syncthreads();

    // one global reservation per (block,bucket); tid==bucket (256==NBKT)
    {
        int b = tid;
        int n = lcnt[b]; if (n > SLOT) n = SLOT;
        lcnt[b] = n;
        lbase[b] = (n > 0) ? atomicAdd(&gcur[b * 8 + shard], n) : 0;
    }
    __syncthreads();

    // R18 flush: 16-lane group per bucket, 4 buckets per wave-iteration.
    int wave = tid >> 6, lane = tid & 63;
    int grp = lane >> 4, l16 = lane & 15;
#pragma unroll 4
    for (int jj = 0; jj < 16; ++jj) {
        int b = wave * 64 + jj * 4 + grp;
        int n = lcnt[b];
        int base = lbase[b];
        int2* dst = &buf1[((size_t)b * 8 + shard) * S1CAP];
        if (l16 < n) {
            int2 rec = slot[b * SSTR + l16];
            int p = base + l16;
            if (p < S1CAP) dst[p] = rec;
            else { int sp = atomicAdd(&gspillc[b], 1);
                   if (sp < SPCAP) spill[b * SPCAP + sp] = rec; }
        }
        if (l16 + 16 < n) {                 // n <= 24, so only lanes 0..7
            int2 rec = slot[b * SSTR + l16 + 16];
            int p = base + l16 + 16;
            if (p < S1CAP) dst[p] = rec;
            else { int sp = atomicAdd(&gspillc[b], 1);
                   if (sp < SPCAP) spill[b * SPCAP + sp] = rec; }
        }
    }
}

// ---------------------------------------------------------------------------
// R18 ELL build (proven). Grid 512 = 2 blocks per bucket (node-halves).
// Counts prefetched in parallel; 8 shards processed concurrently by
// 128-thread groups. Rows zero-padded deg..ceil16(deg).
// ---------------------------------------------------------------------------
__global__ __launch_bounds__(1024) void build_ell(
    const int* __restrict__ gcur, const int2* __restrict__ buf1,
    const int* __restrict__ gspillc, const int2* __restrict__ spill,
    unsigned int* __restrict__ csr, int* __restrict__ cnt)
{
    __shared__ int cur[HPB];
    __shared__ int cnts[9];
    int tid = threadIdx.x;
    int bkt  = blockIdx.x >> 1;
    int nlo  = (blockIdx.x & 1) * HPB;      // this block owns nodes [nlo, nlo+98)

    if (tid < HPB) cur[tid] = 0;
    if (tid >= 128 && tid < 137) {          // parallel count prefetch
        int sh = tid - 128;
        int n = (sh < 8) ? gcur[bkt * 8 + sh] : gspillc[bkt];
        int cap = (sh < 8) ? S1CAP : SPCAP;
        cnts[sh] = n < cap ? n : cap;
    }
    __syncthreads();

    // 8 shards concurrently: 128 threads each
    {
        int sh = tid >> 7, lt = tid & 127;
        int n = cnts[sh];
        const int2* rp = buf1 + ((size_t)bkt * 8 + sh) * S1CAP;
        for (int i = lt; i < n; i += 128) {
            int2 r = rp[i];
            int node = r.y - nlo;
            if ((unsigned)node < HPB) {
                int pos = atomicAdd(&cur[node], 1);
                if (pos < ELLW)
                    csr[((size_t)(bkt * NPB + r.y)) * ELLW + pos] = (unsigned int)r.x;
            }
        }
    }
    // spill region: all threads
    {
        int n = cnts[8];
        const int2* rp = spill + (size_t)bkt * SPCAP;
        for (int i = tid; i < n; i += 1024) {
            int2 r = rp[i];
            int node = r.y - nlo;
            if ((unsigned)node < HPB) {
                int pos = atomicAdd(&cur[node], 1);
                if (pos < ELLW)
                    csr[((size_t)(bkt * NPB + r.y)) * ELLW + pos] = (unsigned int)r.x;
            }
        }
    }
    __syncthreads();

    if (tid < HPB) {
        int node = bkt * NPB + nlo + tid;
        if (node < NN) {
            int deg = cur[tid];
            cnt[node] = deg;
            int c = deg < ELLW ? deg : ELLW;
            int c16 = (c + 15) & ~15;          // <= 80 always
            for (int p = c; p < c16; ++p)
                csr[(size_t)node * ELLW + p] = 0u;
        }
    }
}

// processes one 16-record row chunk (uint4 r) for one node into packed accs
#define PROC16(r, s01, s23)                                                   \
    {                                                                         \
        unsigned int v0 = f8[(r.x & 0xFFFF) * 16 + l16];                      \
        unsigned int v1 = f8[(r.y & 0xFFFF) * 16 + l16];                      \
        unsigned int v2 = f8[(r.z & 0xFFFF) * 16 + l16];                      \
        unsigned int v3 = f8[(r.w & 0xFFFF) * 16 + l16];                      \
        float w0 = __uint_as_float(r.x & 0xFFFF0000u);                        \
        float w1 = __uint_as_float(r.y & 0xFFFF0000u);                        \
        float w2 = __uint_as_float(r.z & 0xFFFF0000u);                        \
        float w3 = __uint_as_float(r.w & 0xFFFF0000u);                        \
        f32x2 lo, hi, wp;                                                     \
        lo = __builtin_amdgcn_cvt_pk_f32_fp8(v0, false);                      \
        hi = __builtin_amdgcn_cvt_pk_f32_fp8(v0, true);                       \
        wp = (f32x2){w0, w0}; s01 += wp * lo; s23 += wp * hi;                 \
        lo = __builtin_amdgcn_cvt_pk_f32_fp8(v1, false);                      \
        hi = __builtin_amdgcn_cvt_pk_f32_fp8(v1, true);                       \
        wp = (f32x2){w1, w1}; s01 += wp * lo; s23 += wp * hi;                 \
        lo = __builtin_amdgcn_cvt_pk_f32_fp8(v2, false);                      \
        hi = __builtin_amdgcn_cvt_pk_f32_fp8(v2, true);                       \
        wp = (f32x2){w2, w2}; s01 += wp * lo; s23 += wp * hi;                 \
        lo = __builtin_amdgcn_cvt_pk_f32_fp8(v3, false);                      \
        hi = __builtin_amdgcn_cvt_pk_f32_fp8(v3, true);                       \
        wp = (f32x2){w3, w3}; s01 += wp * lo; s23 += wp * hi;                 \
    }

// ---------------------------------------------------------------------------
// R21 FUSED layer (measured best): 512 thr, 8 waves, 16 nodes (2 per wave,
// interleaved chains) + one-deep ELL-row prefetch. Weight extract is a
// single AND; packed f32x2 accumulators (v_pk_fma_f32).
// Phase 2 (R7 layouts): waves 0-3 = one 16-col output tile, 4 MFMAs.
// ---------------------------------------------------------------------------
__global__ __launch_bounds__(512) void fused_layer(
    const ushort* __restrict__ Xb,          // self features bf16 [NN][64]
    const unsigned int* __restrict__ f8,    // gather table fp8, 16 uints/row
    const int* __restrict__ cnt, const unsigned int* __restrict__ csr,
    const ushort* __restrict__ Wb, const float* __restrict__ bias,
    float* __restrict__ out, ushort* __restrict__ outb,
    unsigned char* __restrict__ outf8)
{
    __shared__ ushort xL[16][72];
    __shared__ ushort aggL[16][72];
    int tid = threadIdx.x;
    int wave = tid >> 6, lane = tid & 63;   // wave in 0..7
    int g = lane >> 4, l16 = lane & 15;
    int base = blockIdx.x * 16;
    int nodeA = base + wave;                // tile rows 0..7
    int nodeB = base + wave + 8;            // tile rows 8..15

    // stage self rows (independent loads, issued early)
    if (lane < 16) {
        *(ushort4*)&xL[wave][l16 * 4] =
            *(const ushort4*)&Xb[(size_t)nodeA * DD + l16 * 4];
        *(ushort4*)&xL[wave + 8][l16 * 4] =
            *(const ushort4*)&Xb[(size_t)nodeB * DD + l16 * 4];
    }

    // ---- phase 1: aggregate two nodes per wave, pipelined ----
    int ndA = cnt[nodeA], ndB = cnt[nodeB];
    int nA = ndA < ELLW ? ndA : ELLW;
    int nB = ndB < ELLW ? ndB : ELLW;
    int nA16 = (nA + 15) & ~15;             // rows zero-padded to here
    int nB16 = (nB + 15) & ~15;
    int imax = nA16 > nB16 ? nA16 : nB16;
    const unsigned int* __restrict__ rpA = csr + (size_t)nodeA * ELLW + g * 4;
    const unsigned int* __restrict__ rpB = csr + (size_t)nodeB * ELLW + g * 4;
    f32x2 sA01 = {0.f, 0.f}, sA23 = {0.f, 0.f};
    f32x2 sB01 = {0.f, 0.f}, sB23 = {0.f, 0.f};

    // prologue: issue row 0 loads
    uint4 rA, rB;
    if (0 < nA16) rA = *(const uint4*)(rpA);
    if (0 < nB16) rB = *(const uint4*)(rpB);

    for (int i = 0; i < imax; i += 16) {
        // prefetch next iteration's rows (hidden under this iteration)
        uint4 rAn, rBn;
        bool doAn = (i + 16) < nA16, doBn = (i + 16) < nB16;
        if (doAn) rAn = *(const uint4*)(rpA + i + 16);
        if (doBn) rBn = *(const uint4*)(rpB + i + 16);
        if (i < nA16) PROC16(rA, sA01, sA23);
        if (i < nB16) PROC16(rB, sB01, sB23);
        rA = rAn; rB = rBn;
    }

    float aA0 = sA01.x, aA1 = sA01.y, aA2 = sA23.x, aA3 = sA23.y;
    float aB0 = sB01.x, aB1 = sB01.y, aB2 = sB23.x, aB3 = sB23.y;
    aA0 += __shfl_xor(aA0, 16); aA0 += __shfl_xor(aA0, 32);
    aA1 += __shfl_xor(aA1, 16); aA1 += __shfl_xor(aA1, 32);
    aA2 += __shfl_xor(aA2, 16); aA2 += __shfl_xor(aA2, 32);
    aA3 += __shfl_xor(aA3, 16); aA3 += __shfl_xor(aA3, 32);
    aB0 += __shfl_xor(aB0, 16); aB0 += __shfl_xor(aB0, 32);
    aB1 += __shfl_xor(aB1, 16); aB1 += __shfl_xor(aB1, 32);
    aB2 += __shfl_xor(aB2, 16); aB2 += __shfl_xor(aB2, 32);
    aB3 += __shfl_xor(aB3, 16); aB3 += __shfl_xor(aB3, 32);

    if (lane < 16) {
        float dmA = (float)(ndA > 1 ? ndA : 1);
        float dmB = (float)(ndB > 1 ? ndB : 1);
        ushort4 oA, oB;
        oA.x = f2bf(aA0 / dmA); oA.y = f2bf(aA1 / dmA);
        oA.z = f2bf(aA2 / dmA); oA.w = f2bf(aA3 / dmA);
        oB.x = f2bf(aB0 / dmB); oB.y = f2bf(aB1 / dmB);
        oB.z = f2bf(aB2 / dmB); oB.w = f2bf(aB3 / dmB);
        *(ushort4*)&aggL[wave][l16 * 4] = oA;
        *(ushort4*)&aggL[wave + 8][l16 * 4] = oB;
    }
    __syncthreads();

    // ---- phase 2: GEMM (waves 0-3; wave = col tile) ----
    if (wave < 4) {
        f32x4 acc = (f32x4){0.f, 0.f, 0.f, 0.f};
#pragma unroll
        for (int ki = 0; ki < 4; ++ki) {
            const ushort* ap = (ki < 2) ? &xL[l16][ki * 32 + g * 8]
                                        : &aggL[l16][(ki - 2) * 32 + g * 8];
            bf16x8 af = *(const bf16x8*)ap;
            bf16x8 bfrag = *(const bf16x8*)&Wb[(size_t)(wave * 16 + l16) * 128 + ki * 32 + g * 8];
            acc = __builtin_amdgcn_mfma_f32_16x16x32_bf16(af, bfrag, acc, 0, 0, 0);
        }
        int col = wave * 16 + l16;
        float bv = bias[col];
#pragma unroll
        for (int r = 0; r < 4; ++r) {
            int grow = base + g * 4 + r;   // C/D: col=lane&15, row=quad*4+reg
            float v = fmaxf(acc[r] + bv, 0.f);
            if (out)  out[(size_t)grow * DD + col] = v;
            if (outb) outb[(size_t)grow * DD + col] = f2bf(v);
            if (outf8) {
                unsigned int p = __builtin_amdgcn_cvt_pk_fp8_f32(v, v, 0u, false);
                outf8[(size_t)grow * DD + col] = (unsigned char)(p & 0xFFu);
            }
        }
    }
}

// ---------------------------------------------------------------------------
extern "C" void kernel_launch(void* const* d_in, const int* in_sizes, int n_in,
                              void* d_out, int out_size, void* d_ws, size_t ws_size,
                              hipStream_t stream)
{
    const float* x  = (const float*)d_in[0];
    const int*   ei = (const int*)d_in[1];
    const float* ew = (const float*)d_in[2];
    const float* W1 = (const float*)d_in[3];
    const float* b1 = (const float*)d_in[4];
    const float* W2 = (const float*)d_in[5];
    const float* b2 = (const float*)d_in[6];
    float* out = (float*)d_out;

    // workspace layout, ~53.3 MB (16B-aligned offsets)
    char* ws = (char*)d_ws;
    int*          gcur    = (int*)ws;                          //      8,192 B
    int*          gspillc = (int*)(ws + 8192);                 //      1,024 B
    int2*         buf1    = (int2*)(ws + 16384);               // 16,777,216 B
    int2*         spill   = (int2*)(ws + 16793600);            //  1,048,576 B
    unsigned int* csr     = (unsigned int*)(ws + 17842176);    // 16,056,320 B (ELL 80/node)
    int*          cnt     = (int*)(ws + 33898496);             //    200,704 B
    ushort*       xb      = (ushort*)(ws + 34099200);          //  6,400,000 B
    ushort*       h1b     = (ushort*)(ws + 40499200);          //  6,400,000 B
    ushort*       W1b     = (ushort*)(ws + 46899200);          //     16,384 B
    ushort*       W2b     = (ushort*)(ws + 46915584);          //     16,384 B
    unsigned int* xf8     = (unsigned int*)(ws + 46931968);    //  3,200,000 B
    unsigned char* h1f8   = (unsigned char*)(ws + 50131968);   //  3,200,000 B

    hipMemsetAsync(gcur, 0, 9216, stream);   // gcur + gspillc

    prep_bin<<<NBLK + 3141, 256, 0, stream>>>(ei, ew, gcur, gspillc, buf1, spill,
                                              x, xb, xf8, W1, W2, W1b, W2b);
    build_ell<<<NBKT * 2, 1024, 0, stream>>>(gcur, buf1, gspillc, spill, csr, cnt);

    // layer 1: gather fp8(x), self bf16(x) -> h1b + h1f8
    fused_layer<<<NN / 16, 512, 0, stream>>>(xb, xf8, cnt, csr, W1b, b1,
                                             nullptr, h1b, h1f8);
    // layer 2: gather fp8(h1), self bf16(h1) -> out
    fused_layer<<<NN / 16, 512, 0, stream>>>(h1b, (const unsigned int*)h1f8,
                                             cnt, csr, W2b, b2, out, nullptr, nullptr);
}